// Round 17
// baseline (83.089 us; speedup 1.0000x reference)
//
#include <hip/hip_runtime.h>
#include <hip/hip_bf16.h>

// Problem constants
constexpr int BATCH = 4;
constexpr int SEQ   = 4096;
constexpr int DIM   = 128;   // head size

// Split-KV: KV tiles are 64 keys; CHUNK tiles per split block (templated).
constexpr size_t QKV_BYTES = (size_t)3 * BATCH * SEQ * DIM * 2;
// partial slot: m[64] f32, l[64] f32, O[64][128] bf16
constexpr size_t SLOT_BYTES = 64 * 4 + 64 * 4 + 64 * 128 * 2;   // 16896

constexpr int tasks_per_b(int chunk) {
    return chunk * (64 / chunk) * (64 / chunk + 1) / 2;
}
constexpr size_t part_bytes(int chunk) {
    return (size_t)BATCH * tasks_per_b(chunk) * SLOT_BYTES;
}

typedef __bf16 bf16x8 __attribute__((ext_vector_type(8)));
typedef __bf16 bf16x4 __attribute__((ext_vector_type(4)));
typedef float  f32x4  __attribute__((ext_vector_type(4)));

// ---------------------------------------------------------------------------
// Kernel 1: QKV projection, 64-row blocks. Grid (256, 3) = 768 blocks.
// (R16-proven: swizzled Wt transpose writes + staged coalesced stores.)
// ---------------------------------------------------------------------------
__global__ __launch_bounds__(256) void qkv_proj(
    const float* __restrict__ x,
    const float* __restrict__ Wq, const float* __restrict__ Wk,
    const float* __restrict__ Wv,
    __bf16* __restrict__ q, __bf16* __restrict__ k, __bf16* __restrict__ v)
{
    __shared__ __align__(16) __bf16 Xl[64][136];    // X tile; then O staging
    __shared__ __align__(16) __bf16 Wt[128][136];   // W transposed: Wt[d][c^swz(d)]

    const int t    = threadIdx.x;
    const int lane = t & 63;
    const int w    = t >> 6;
    const int l15  = lane & 15;
    const int l4   = lane >> 4;
    const int rowblk = blockIdx.x * 64;
    const int m      = blockIdx.y;

    const float* W  = (m == 0) ? Wq : (m == 1) ? Wk : Wv;
    __bf16*      op = (m == 0) ? q  : (m == 1) ? k  : v;

    #pragma unroll
    for (int i = 0; i < 8; ++i) {
        int idx = i * 256 + t;
        int r   = idx >> 5;
        int c4  = (idx & 31) << 2;
        float4 f = *(const float4*)(x + (size_t)(rowblk + r) * DIM + c4);
        __bf16* dst = &Xl[r][c4];
        dst[0] = (__bf16)f.x; dst[1] = (__bf16)f.y;
        dst[2] = (__bf16)f.z; dst[3] = (__bf16)f.w;
    }
    #pragma unroll
    for (int i = 0; i < 16; ++i) {
        int idx = i * 256 + t;
        int r   = idx >> 5;          // c index
        int c4  = (idx & 31) << 2;   // d base
        float4 f = *(const float4*)(W + (size_t)r * DIM + c4);
        #pragma unroll
        for (int e = 0; e < 4; ++e) {
            int d  = c4 + e;
            int cs = r ^ (8 * ((d >> 2) & 7));
            Wt[d][cs] = (e == 0) ? (__bf16)f.x : (e == 1) ? (__bf16)f.y
                       : (e == 2) ? (__bf16)f.z : (__bf16)f.w;
        }
    }
    __syncthreads();

    f32x4 acc[8];
    #pragma unroll
    for (int cf = 0; cf < 8; ++cf) acc[cf] = (f32x4){0.f, 0.f, 0.f, 0.f};

    #pragma unroll
    for (int kc = 0; kc < 4; ++kc) {
        bf16x8 af = *(const bf16x8*)&Xl[w * 16 + l15][kc * 32 + l4 * 8];
        #pragma unroll
        for (int cf = 0; cf < 8; ++cf) {
            int d   = cf * 16 + l15;
            int cb  = (kc * 32 + l4 * 8) ^ (8 * ((d >> 2) & 7));
            bf16x8 bfr = *(const bf16x8*)&Wt[d][cb];
            acc[cf] = __builtin_amdgcn_mfma_f32_16x16x32_bf16(af, bfr, acc[cf], 0, 0, 0);
        }
    }

    __syncthreads();   // all waves done reading Xl/Wt

    #pragma unroll
    for (int cf = 0; cf < 8; ++cf)
        #pragma unroll
        for (int r2 = 0; r2 < 4; ++r2) {
            int rowl = w * 16 + l4 * 4 + r2;
            int col  = cf * 16 + l15;
            Xl[rowl][col ^ (8 * ((rowl >> 2) & 3))] = (__bf16)acc[cf][r2];
        }
    __syncthreads();

    {
        int rowl = t >> 2;
        int sw   = 8 * ((rowl >> 2) & 3);
        __bf16* orow = op + (size_t)(rowblk + rowl) * DIM;
        #pragma unroll
        for (int u = 0; u < 4; ++u) {
            int col8 = u * 32 + (t & 3) * 8;
            bf16x8 vv = *(const bf16x8*)&Xl[rowl][col8 ^ sw];
            *(bf16x8*)(orow + col8) = vv;
        }
    }
}

// ---------------------------------------------------------------------------
// Kernel 2: causal flash attention, split-KV. EXACT R12/R15/R16 kernel body
// (attn 59.5us, 4x verified). R17's only change: LPT block ordering --
// j = TASKS-1-blockIdx.x, so long (full-chunk) tasks launch FIRST and the
// drain tail consists of the short stub tasks (makespan / LPT argument).
// ---------------------------------------------------------------------------
template <bool SPLIT, int CHUNK>
__global__ __launch_bounds__(256) void attn(
    const __bf16* __restrict__ q, const __bf16* __restrict__ k,
    const __bf16* __restrict__ v, float* __restrict__ out,
    char* __restrict__ part)
{
    constexpr int NG    = 64 / CHUNK;
    constexpr int TASKS = tasks_per_b(CHUNK);

    __shared__ __align__(16) __bf16 KlBuf[64 * 136];   // Kl in QK^T phase; Pl in PV phase
    __shared__ __align__(16) __bf16 Vt[128][72];

    typedef __bf16 (*KlT)[136];
    typedef __bf16 (*PlT)[16][72];
    KlT Kl = (KlT)KlBuf;            // [64][136]
    PlT Pl = (PlT)KlBuf;            // [4][16][72] = 9216 B

    const int t    = threadIdx.x;
    const int lane = t & 63;
    const int w    = t >> 6;
    const int l15  = lane & 15;
    const int l4   = lane >> 4;
    const int b    = blockIdx.y;

    int qt, chunk, nch, slot = 0;
    if (SPLIT) {
        int j = TASKS - 1 - blockIdx.x;     // LPT: long tasks first, stubs last
        int g = 0;
        while (g < NG - 1 && j >= CHUNK * (g + 1) * (g + 2) / 2) ++g;
        int r = j - CHUNK * g * (g + 1) / 2;
        nch   = g + 1;
        qt    = CHUNK * g + r / nch;
        chunk = r - (r / nch) * nch;
        slot  = b * TASKS + j;
    } else {
        qt = blockIdx.x; chunk = 0; nch = 1;
    }
    const int qb0 = qt * 64;
    const int jt0 = chunk * CHUNK;
    const int jtE = SPLIT ? min(jt0 + CHUNK, qt + 1) : qt + 1;
    const size_t base = (size_t)b * SEQ * DIM;

    // staging geometry
    const int rr = t >> 4;             // 0..15  (K rows)
    const int c  = (t & 15) * 8;       // K d-base
    const int vp = t >> 5;             // 0..7   (V pair id within group)
    const int vd = (t & 31) * 4;       // V d-base

    // Q fragments (A-operand layout: row = l15, k = l4*8 + j + 32*dc)
    bf16x8 qf[4];
    {
        const __bf16* qrow = q + base + (size_t)(qb0 + w * 16 + l15) * DIM;
        #pragma unroll
        for (int dc = 0; dc < 4; ++dc)
            qf[dc] = *(const bf16x8*)(qrow + dc * 32 + l4 * 8);
    }

    f32x4 o[8];
    #pragma unroll
    for (int i = 0; i < 8; ++i) o[i] = (f32x4){0.f, 0.f, 0.f, 0.f};
    float mr[4], lr[4];
    #pragma unroll
    for (int r = 0; r < 4; ++r) { mr[r] = -INFINITY; lr[r] = 0.f; }

    const float scale = 0.08838834764831845f;  // 1/sqrt(128)

    for (int jt = jt0; jt < jtE; ++jt) {
        __syncthreads();   // B1: all waves done with Pl(=KlBuf)/Vt of prev tile

        // ---- load K (linear, padded) and V (pi-permuted pair-packed) ----
        {
            const __bf16* kg = k + base + (size_t)jt * 64 * DIM;
            const __bf16* vg = v + base + (size_t)jt * 64 * DIM;
            #pragma unroll
            for (int i = 0; i < 4; ++i) {
                int row = i * 16 + rr;
                *(int4*)&Kl[row][c] = *(const int4*)(kg + (size_t)row * DIM + c);
                // V: pair (ka, ka+16) -> adjacent new indices (kn, kn+1)
                int p    = i * 8 + vp;        // pair id 0..31
                int l15_ = p >> 1;
                int kcp  = p & 1;
                int ka   = 32 * kcp + l15_;   // old key (even new slot)
                int kn   = 4 * l15_ + 2 * kcp;// permuted index, even
                ushort4 va = *(const ushort4*)(vg + (size_t)ka * DIM + vd);
                ushort4 vb = *(const ushort4*)(vg + (size_t)(ka + 16) * DIM + vd);
                #pragma unroll
                for (int e = 0; e < 4; ++e) {
                    int cc  = vd + e;                                  // d index
                    int col = (((kn >> 3) ^ ((cc >> 3) & 7)) << 3) | (kn & 7);
                    ushort2 pr;
                    pr.x = (&va.x)[e];
                    pr.y = (&vb.x)[e];
                    *(ushort2*)&Vt[cc][col] = pr;
                }
            }
        }
        __syncthreads();   // B2: Kl/Vt visible

        // ---- S = Q K^T ----
        f32x4 s[4];
        __builtin_amdgcn_s_setprio(1);
        #pragma unroll
        for (int kc = 0; kc < 4; ++kc) {
            f32x4 acc = (f32x4){0.f, 0.f, 0.f, 0.f};
            #pragma unroll
            for (int dc = 0; dc < 4; ++dc) {
                bf16x8 kf = *(const bf16x8*)&Kl[kc * 16 + l15][dc * 32 + l4 * 8];
                acc = __builtin_amdgcn_mfma_f32_16x16x32_bf16(qf[dc], kf, acc, 0, 0, 0);
            }
            s[kc] = acc;
        }
        __builtin_amdgcn_s_setprio(0);

        // ---- scale + causal mask + online softmax ----
        const bool diag = (jt == qt);
        float rowmax[4];
        #pragma unroll
        for (int r = 0; r < 4; ++r) rowmax[r] = -INFINITY;
        #pragma unroll
        for (int kc = 0; kc < 4; ++kc) {
            int key = jt * 64 + kc * 16 + l15;
            #pragma unroll
            for (int r = 0; r < 4; ++r) {
                float sv = s[kc][r] * scale;
                if (diag) {
                    int qrow = qb0 + w * 16 + l4 * 4 + r;
                    if (key > qrow) sv = -INFINITY;
                }
                s[kc][r] = sv;
                rowmax[r] = fmaxf(rowmax[r], sv);
            }
        }
        #pragma unroll
        for (int r = 0; r < 4; ++r) {
            float x2 = rowmax[r];
            x2 = fmaxf(x2, __shfl_xor(x2, 1));
            x2 = fmaxf(x2, __shfl_xor(x2, 2));
            x2 = fmaxf(x2, __shfl_xor(x2, 4));
            x2 = fmaxf(x2, __shfl_xor(x2, 8));
            rowmax[r] = x2;
        }
        float alpha[4];
        #pragma unroll
        for (int r = 0; r < 4; ++r) {
            float mnew = fmaxf(mr[r], rowmax[r]);
            alpha[r]   = __expf(mr[r] - mnew);
            mr[r]      = mnew;
        }
        float rowsum[4] = {0.f, 0.f, 0.f, 0.f};
        #pragma unroll
        for (int kc = 0; kc < 4; ++kc)
            #pragma unroll
            for (int r = 0; r < 4; ++r) {
                float p = __expf(s[kc][r] - mr[r]);
                s[kc][r] = p;
                rowsum[r] += p;
            }
        #pragma unroll
        for (int r = 0; r < 4; ++r) {
            float x2 = rowsum[r];
            x2 += __shfl_xor(x2, 1);
            x2 += __shfl_xor(x2, 2);
            x2 += __shfl_xor(x2, 4);
            x2 += __shfl_xor(x2, 8);
            lr[r] = lr[r] * alpha[r] + x2;
        }
        #pragma unroll
        for (int df = 0; df < 8; ++df)
            #pragma unroll
            for (int r = 0; r < 4; ++r) o[df][r] *= alpha[r];

        __syncthreads();   // B3: all waves done reading Kl before Pl overwrite

        // ---- P -> Pl in pi-permuted layout: 4x ds_write_b64 ----
        #pragma unroll
        for (int r = 0; r < 4; ++r) {
            bf16x4 pk;
            #pragma unroll
            for (int kc = 0; kc < 4; ++kc) pk[kc] = (__bf16)s[kc][r];
            *(bf16x4*)&Pl[w][l4 * 4 + r][l15 * 4] = pk;
        }

        // ---- O += P V (both operands enumerate pi(k)) ----
        __builtin_amdgcn_s_setprio(1);
        #pragma unroll
        for (int pc = 0; pc < 2; ++pc) {
            bf16x8 pa = *(const bf16x8*)&Pl[w][l15][pc * 32 + l4 * 8];
            #pragma unroll
            for (int df = 0; df < 8; ++df) {
                int cc  = df * 16 + l15;
                int kch = (pc * 4 + l4) ^ ((cc >> 3) & 7);
                bf16x8 vf = *(const bf16x8*)&Vt[cc][kch * 8];
                o[df] = __builtin_amdgcn_mfma_f32_16x16x32_bf16(pa, vf, o[df], 0, 0, 0);
            }
        }
        __builtin_amdgcn_s_setprio(0);
    }

    if (!SPLIT || nch == 1) {
        float inv[4];
        #pragma unroll
        for (int r = 0; r < 4; ++r) inv[r] = 1.0f / lr[r];
        float* op = out + base;
        #pragma unroll
        for (int df = 0; df < 8; ++df)
            #pragma unroll
            for (int r = 0; r < 4; ++r) {
                int row = qb0 + w * 16 + l4 * 4 + r;
                op[(size_t)row * DIM + df * 16 + l15] = o[df][r] * inv[r];
            }
    } else {
        char* sp = part + (size_t)slot * SLOT_BYTES;
        float*  smp = (float*)sp;           // m[64]
        float*  slp = (float*)(sp + 256);   // l[64]
        __bf16* sop = (__bf16*)(sp + 512);  // O[64][128] bf16
        #pragma unroll
        for (int r = 0; r < 4; ++r) {
            int rl = w * 16 + l4 * 4 + r;
            if (l15 == 0) { smp[rl] = mr[r]; slp[rl] = lr[r]; }
        }
        #pragma unroll
        for (int df = 0; df < 8; ++df)
            #pragma unroll
            for (int r = 0; r < 4; ++r) {
                int rl = w * 16 + l4 * 4 + r;
                sop[(size_t)rl * 128 + df * 16 + l15] = (__bf16)o[df][r];
            }
    }
}

// ---------------------------------------------------------------------------
// Kernel 3: combine partials for qt >= CHUNK. Grid ((64-CHUNK)*4, B); each
// block does a 16-row quarter of one qt (R15-proven parallel form).
// ---------------------------------------------------------------------------
template <int CHUNK>
__global__ __launch_bounds__(256) void combine(
    const char* __restrict__ part, float* __restrict__ out)
{
    constexpr int TASKS = tasks_per_b(CHUNK);

    const int qt  = (blockIdx.x >> 2) + CHUNK;
    const int qr  = blockIdx.x & 3;          // row quarter
    const int b   = blockIdx.y;
    const int g   = qt / CHUNK;
    const int nch = g + 1;
    const int slot0 = b * TASKS + CHUNK * g * (g + 1) / 2 + (qt % CHUNK) * nch;

    const int t   = threadIdx.x;
    const int row = qr * 16 + (t >> 4);      // 0..63
    const int c0  = (t & 15) * 8;            // 8-col strip

    float M = -INFINITY;
    for (int c = 0; c < nch; ++c) {
        const char* sp = part + (size_t)(slot0 + c) * SLOT_BYTES;
        M = fmaxf(M, ((const float*)sp)[row]);
    }
    float L = 0.f;
    for (int c = 0; c < nch; ++c) {
        const char* sp = part + (size_t)(slot0 + c) * SLOT_BYTES;
        L += ((const float*)(sp + 256))[row] * __expf(((const float*)sp)[row] - M);
    }

    float acc[8];
    #pragma unroll
    for (int i = 0; i < 8; ++i) acc[i] = 0.f;
    for (int c = 0; c < nch; ++c) {
        const char* sp = part + (size_t)(slot0 + c) * SLOT_BYTES;
        float wgt = __expf(((const float*)sp)[row] - M);
        const __bf16* op = (const __bf16*)(sp + 512) + (size_t)row * 128 + c0;
        bf16x8 vv = *(const bf16x8*)op;
        #pragma unroll
        for (int j = 0; j < 8; ++j)
            acc[j] += wgt * (float)vv[j];
    }
    float invL = 1.0f / L;
    float* o = out + ((size_t)b * SEQ + (size_t)qt * 64 + row) * DIM + c0;
    float4 f0, f1;
    f0.x = acc[0] * invL; f0.y = acc[1] * invL;
    f0.z = acc[2] * invL; f0.w = acc[3] * invL;
    f1.x = acc[4] * invL; f1.y = acc[5] * invL;
    f1.z = acc[6] * invL; f1.w = acc[7] * invL;
    *(float4*)o = f0;
    *(float4*)(o + 4) = f1;
}

// ---------------------------------------------------------------------------
extern "C" void kernel_launch(void* const* d_in, const int* in_sizes, int n_in,
                              void* d_out, int out_size, void* d_ws, size_t ws_size,
                              hipStream_t stream) {
    const float* x  = (const float*)d_in[0];
    const float* Wq = (const float*)d_in[1];
    const float* Wk = (const float*)d_in[2];
    const float* Wv = (const float*)d_in[3];
    float* out = (float*)d_out;

    __bf16* qw = (__bf16*)d_ws;
    __bf16* kw = qw + (size_t)BATCH * SEQ * DIM;
    __bf16* vw = kw + (size_t)BATCH * SEQ * DIM;
    char*   part = (char*)d_ws + QKV_BYTES;

    qkv_proj<<<dim3(BATCH * SEQ / 64, 3), 256, 0, stream>>>(x, Wq, Wk, Wv, qw, kw, vw);

    if (ws_size >= QKV_BYTES + part_bytes(4)) {
        attn<true, 4><<<dim3(tasks_per_b(4), BATCH), 256, 0, stream>>>(qw, kw, vw, out, part);
        combine<4><<<dim3(60 * 4, BATCH), 256, 0, stream>>>(part, out);
    } else if (ws_size >= QKV_BYTES + part_bytes(8)) {
        attn<true, 8><<<dim3(tasks_per_b(8), BATCH), 256, 0, stream>>>(qw, kw, vw, out, part);
        combine<8><<<dim3(56 * 4, BATCH), 256, 0, stream>>>(part, out);
    } else {
        attn<false, 8><<<dim3(SEQ / 64, BATCH), 256, 0, stream>>>(qw, kw, vw, out, part);
    }
}

// Round 18
// 82.466 us; speedup vs baseline: 1.0076x; 1.0076x over previous
//
#include <hip/hip_runtime.h>
#include <hip/hip_bf16.h>

// Problem constants
constexpr int BATCH = 4;
constexpr int SEQ   = 4096;
constexpr int DIM   = 128;   // head size

// Split-KV: KV tiles are 64 keys; CHUNK tiles per split block (templated).
constexpr size_t QKV_BYTES = (size_t)3 * BATCH * SEQ * DIM * 2;
// partial slot: m[64] f32, l[64] f32, O[64][128] bf16
constexpr size_t SLOT_BYTES = 64 * 4 + 64 * 4 + 64 * 128 * 2;   // 16896

constexpr int tasks_per_b(int chunk) {
    return chunk * (64 / chunk) * (64 / chunk + 1) / 2;
}
constexpr size_t part_bytes(int chunk) {
    return (size_t)BATCH * tasks_per_b(chunk) * SLOT_BYTES;
}

typedef __bf16 bf16x8 __attribute__((ext_vector_type(8)));
typedef __bf16 bf16x4 __attribute__((ext_vector_type(4)));
typedef float  f32x4  __attribute__((ext_vector_type(4)));

// ---------------------------------------------------------------------------
// Kernel 1: QKV projection, 64-row blocks. Grid (256, 3) = 768 blocks.
// (R16-proven: swizzled Wt transpose writes + staged coalesced stores.)
// ---------------------------------------------------------------------------
__global__ __launch_bounds__(256) void qkv_proj(
    const float* __restrict__ x,
    const float* __restrict__ Wq, const float* __restrict__ Wk,
    const float* __restrict__ Wv,
    __bf16* __restrict__ q, __bf16* __restrict__ k, __bf16* __restrict__ v)
{
    __shared__ __align__(16) __bf16 Xl[64][136];    // X tile; then O staging
    __shared__ __align__(16) __bf16 Wt[128][136];   // W transposed: Wt[d][c^swz(d)]

    const int t    = threadIdx.x;
    const int lane = t & 63;
    const int w    = t >> 6;
    const int l15  = lane & 15;
    const int l4   = lane >> 4;
    const int rowblk = blockIdx.x * 64;
    const int m      = blockIdx.y;

    const float* W  = (m == 0) ? Wq : (m == 1) ? Wk : Wv;
    __bf16*      op = (m == 0) ? q  : (m == 1) ? k  : v;

    #pragma unroll
    for (int i = 0; i < 8; ++i) {
        int idx = i * 256 + t;
        int r   = idx >> 5;
        int c4  = (idx & 31) << 2;
        float4 f = *(const float4*)(x + (size_t)(rowblk + r) * DIM + c4);
        __bf16* dst = &Xl[r][c4];
        dst[0] = (__bf16)f.x; dst[1] = (__bf16)f.y;
        dst[2] = (__bf16)f.z; dst[3] = (__bf16)f.w;
    }
    #pragma unroll
    for (int i = 0; i < 16; ++i) {
        int idx = i * 256 + t;
        int r   = idx >> 5;          // c index
        int c4  = (idx & 31) << 2;   // d base
        float4 f = *(const float4*)(W + (size_t)r * DIM + c4);
        #pragma unroll
        for (int e = 0; e < 4; ++e) {
            int d  = c4 + e;
            int cs = r ^ (8 * ((d >> 2) & 7));
            Wt[d][cs] = (e == 0) ? (__bf16)f.x : (e == 1) ? (__bf16)f.y
                       : (e == 2) ? (__bf16)f.z : (__bf16)f.w;
        }
    }
    __syncthreads();

    f32x4 acc[8];
    #pragma unroll
    for (int cf = 0; cf < 8; ++cf) acc[cf] = (f32x4){0.f, 0.f, 0.f, 0.f};

    #pragma unroll
    for (int kc = 0; kc < 4; ++kc) {
        bf16x8 af = *(const bf16x8*)&Xl[w * 16 + l15][kc * 32 + l4 * 8];
        #pragma unroll
        for (int cf = 0; cf < 8; ++cf) {
            int d   = cf * 16 + l15;
            int cb  = (kc * 32 + l4 * 8) ^ (8 * ((d >> 2) & 7));
            bf16x8 bfr = *(const bf16x8*)&Wt[d][cb];
            acc[cf] = __builtin_amdgcn_mfma_f32_16x16x32_bf16(af, bfr, acc[cf], 0, 0, 0);
        }
    }

    __syncthreads();   // all waves done reading Xl/Wt

    #pragma unroll
    for (int cf = 0; cf < 8; ++cf)
        #pragma unroll
        for (int r2 = 0; r2 < 4; ++r2) {
            int rowl = w * 16 + l4 * 4 + r2;
            int col  = cf * 16 + l15;
            Xl[rowl][col ^ (8 * ((rowl >> 2) & 3))] = (__bf16)acc[cf][r2];
        }
    __syncthreads();

    {
        int rowl = t >> 2;
        int sw   = 8 * ((rowl >> 2) & 3);
        __bf16* orow = op + (size_t)(rowblk + rowl) * DIM;
        #pragma unroll
        for (int u = 0; u < 4; ++u) {
            int col8 = u * 32 + (t & 3) * 8;
            bf16x8 vv = *(const bf16x8*)&Xl[rowl][col8 ^ sw];
            *(bf16x8*)(orow + col8) = vv;
        }
    }
}

// ---------------------------------------------------------------------------
// Kernel 2: causal flash attention, split-KV. EXACT R12/R15/R16 kernel body
// (attn 59.5us, 5x verified). R18's only change vs R16: XCD-aware block
// swizzle j = (bid%8)*(TASKS/8) + bid/8 (bijective; TASKS%8==0 for CHUNK
// in {4,8}) so same-XCD blocks process consecutive tasks and share K/V
// panels in their private L2 (T1; mechanism = load-latency reduction).
// ---------------------------------------------------------------------------
template <bool SPLIT, int CHUNK>
__global__ __launch_bounds__(256) void attn(
    const __bf16* __restrict__ q, const __bf16* __restrict__ k,
    const __bf16* __restrict__ v, float* __restrict__ out,
    char* __restrict__ part)
{
    constexpr int NG    = 64 / CHUNK;
    constexpr int TASKS = tasks_per_b(CHUNK);
    static_assert(!SPLIT || (TASKS % 8 == 0), "XCD swizzle requires TASKS%8==0");

    __shared__ __align__(16) __bf16 KlBuf[64 * 136];   // Kl in QK^T phase; Pl in PV phase
    __shared__ __align__(16) __bf16 Vt[128][72];

    typedef __bf16 (*KlT)[136];
    typedef __bf16 (*PlT)[16][72];
    KlT Kl = (KlT)KlBuf;            // [64][136]
    PlT Pl = (PlT)KlBuf;            // [4][16][72] = 9216 B

    const int t    = threadIdx.x;
    const int lane = t & 63;
    const int w    = t >> 6;
    const int l15  = lane & 15;
    const int l4   = lane >> 4;
    const int b    = blockIdx.y;

    int qt, chunk, nch, slot = 0;
    if (SPLIT) {
        // XCD swizzle: consecutive j land on the same XCD (round-robin dispatch)
        int j = (blockIdx.x % 8) * (TASKS / 8) + blockIdx.x / 8;
        int g = 0;
        while (g < NG - 1 && j >= CHUNK * (g + 1) * (g + 2) / 2) ++g;
        int r = j - CHUNK * g * (g + 1) / 2;
        nch   = g + 1;
        qt    = CHUNK * g + r / nch;
        chunk = r - (r / nch) * nch;
        slot  = b * TASKS + j;
    } else {
        qt = blockIdx.x; chunk = 0; nch = 1;
    }
    const int qb0 = qt * 64;
    const int jt0 = chunk * CHUNK;
    const int jtE = SPLIT ? min(jt0 + CHUNK, qt + 1) : qt + 1;
    const size_t base = (size_t)b * SEQ * DIM;

    // staging geometry
    const int rr = t >> 4;             // 0..15  (K rows)
    const int c  = (t & 15) * 8;       // K d-base
    const int vp = t >> 5;             // 0..7   (V pair id within group)
    const int vd = (t & 31) * 4;       // V d-base

    // Q fragments (A-operand layout: row = l15, k = l4*8 + j + 32*dc)
    bf16x8 qf[4];
    {
        const __bf16* qrow = q + base + (size_t)(qb0 + w * 16 + l15) * DIM;
        #pragma unroll
        for (int dc = 0; dc < 4; ++dc)
            qf[dc] = *(const bf16x8*)(qrow + dc * 32 + l4 * 8);
    }

    f32x4 o[8];
    #pragma unroll
    for (int i = 0; i < 8; ++i) o[i] = (f32x4){0.f, 0.f, 0.f, 0.f};
    float mr[4], lr[4];
    #pragma unroll
    for (int r = 0; r < 4; ++r) { mr[r] = -INFINITY; lr[r] = 0.f; }

    const float scale = 0.08838834764831845f;  // 1/sqrt(128)

    for (int jt = jt0; jt < jtE; ++jt) {
        __syncthreads();   // B1: all waves done with Pl(=KlBuf)/Vt of prev tile

        // ---- load K (linear, padded) and V (pi-permuted pair-packed) ----
        {
            const __bf16* kg = k + base + (size_t)jt * 64 * DIM;
            const __bf16* vg = v + base + (size_t)jt * 64 * DIM;
            #pragma unroll
            for (int i = 0; i < 4; ++i) {
                int row = i * 16 + rr;
                *(int4*)&Kl[row][c] = *(const int4*)(kg + (size_t)row * DIM + c);
                // V: pair (ka, ka+16) -> adjacent new indices (kn, kn+1)
                int p    = i * 8 + vp;        // pair id 0..31
                int l15_ = p >> 1;
                int kcp  = p & 1;
                int ka   = 32 * kcp + l15_;   // old key (even new slot)
                int kn   = 4 * l15_ + 2 * kcp;// permuted index, even
                ushort4 va = *(const ushort4*)(vg + (size_t)ka * DIM + vd);
                ushort4 vb = *(const ushort4*)(vg + (size_t)(ka + 16) * DIM + vd);
                #pragma unroll
                for (int e = 0; e < 4; ++e) {
                    int cc  = vd + e;                                  // d index
                    int col = (((kn >> 3) ^ ((cc >> 3) & 7)) << 3) | (kn & 7);
                    ushort2 pr;
                    pr.x = (&va.x)[e];
                    pr.y = (&vb.x)[e];
                    *(ushort2*)&Vt[cc][col] = pr;
                }
            }
        }
        __syncthreads();   // B2: Kl/Vt visible

        // ---- S = Q K^T ----
        f32x4 s[4];
        __builtin_amdgcn_s_setprio(1);
        #pragma unroll
        for (int kc = 0; kc < 4; ++kc) {
            f32x4 acc = (f32x4){0.f, 0.f, 0.f, 0.f};
            #pragma unroll
            for (int dc = 0; dc < 4; ++dc) {
                bf16x8 kf = *(const bf16x8*)&Kl[kc * 16 + l15][dc * 32 + l4 * 8];
                acc = __builtin_amdgcn_mfma_f32_16x16x32_bf16(qf[dc], kf, acc, 0, 0, 0);
            }
            s[kc] = acc;
        }
        __builtin_amdgcn_s_setprio(0);

        // ---- scale + causal mask + online softmax ----
        const bool diag = (jt == qt);
        float rowmax[4];
        #pragma unroll
        for (int r = 0; r < 4; ++r) rowmax[r] = -INFINITY;
        #pragma unroll
        for (int kc = 0; kc < 4; ++kc) {
            int key = jt * 64 + kc * 16 + l15;
            #pragma unroll
            for (int r = 0; r < 4; ++r) {
                float sv = s[kc][r] * scale;
                if (diag) {
                    int qrow = qb0 + w * 16 + l4 * 4 + r;
                    if (key > qrow) sv = -INFINITY;
                }
                s[kc][r] = sv;
                rowmax[r] = fmaxf(rowmax[r], sv);
            }
        }
        #pragma unroll
        for (int r = 0; r < 4; ++r) {
            float x2 = rowmax[r];
            x2 = fmaxf(x2, __shfl_xor(x2, 1));
            x2 = fmaxf(x2, __shfl_xor(x2, 2));
            x2 = fmaxf(x2, __shfl_xor(x2, 4));
            x2 = fmaxf(x2, __shfl_xor(x2, 8));
            rowmax[r] = x2;
        }
        float alpha[4];
        #pragma unroll
        for (int r = 0; r < 4; ++r) {
            float mnew = fmaxf(mr[r], rowmax[r]);
            alpha[r]   = __expf(mr[r] - mnew);
            mr[r]      = mnew;
        }
        float rowsum[4] = {0.f, 0.f, 0.f, 0.f};
        #pragma unroll
        for (int kc = 0; kc < 4; ++kc)
            #pragma unroll
            for (int r = 0; r < 4; ++r) {
                float p = __expf(s[kc][r] - mr[r]);
                s[kc][r] = p;
                rowsum[r] += p;
            }
        #pragma unroll
        for (int r = 0; r < 4; ++r) {
            float x2 = rowsum[r];
            x2 += __shfl_xor(x2, 1);
            x2 += __shfl_xor(x2, 2);
            x2 += __shfl_xor(x2, 4);
            x2 += __shfl_xor(x2, 8);
            lr[r] = lr[r] * alpha[r] + x2;
        }
        #pragma unroll
        for (int df = 0; df < 8; ++df)
            #pragma unroll
            for (int r = 0; r < 4; ++r) o[df][r] *= alpha[r];

        __syncthreads();   // B3: all waves done reading Kl before Pl overwrite

        // ---- P -> Pl in pi-permuted layout: 4x ds_write_b64 ----
        #pragma unroll
        for (int r = 0; r < 4; ++r) {
            bf16x4 pk;
            #pragma unroll
            for (int kc = 0; kc < 4; ++kc) pk[kc] = (__bf16)s[kc][r];
            *(bf16x4*)&Pl[w][l4 * 4 + r][l15 * 4] = pk;
        }

        // ---- O += P V (both operands enumerate pi(k)) ----
        __builtin_amdgcn_s_setprio(1);
        #pragma unroll
        for (int pc = 0; pc < 2; ++pc) {
            bf16x8 pa = *(const bf16x8*)&Pl[w][l15][pc * 32 + l4 * 8];
            #pragma unroll
            for (int df = 0; df < 8; ++df) {
                int cc  = df * 16 + l15;
                int kch = (pc * 4 + l4) ^ ((cc >> 3) & 7);
                bf16x8 vf = *(const bf16x8*)&Vt[cc][kch * 8];
                o[df] = __builtin_amdgcn_mfma_f32_16x16x32_bf16(pa, vf, o[df], 0, 0, 0);
            }
        }
        __builtin_amdgcn_s_setprio(0);
    }

    if (!SPLIT || nch == 1) {
        float inv[4];
        #pragma unroll
        for (int r = 0; r < 4; ++r) inv[r] = 1.0f / lr[r];
        float* op = out + base;
        #pragma unroll
        for (int df = 0; df < 8; ++df)
            #pragma unroll
            for (int r = 0; r < 4; ++r) {
                int row = qb0 + w * 16 + l4 * 4 + r;
                op[(size_t)row * DIM + df * 16 + l15] = o[df][r] * inv[r];
            }
    } else {
        char* sp = part + (size_t)slot * SLOT_BYTES;
        float*  smp = (float*)sp;           // m[64]
        float*  slp = (float*)(sp + 256);   // l[64]
        __bf16* sop = (__bf16*)(sp + 512);  // O[64][128] bf16
        #pragma unroll
        for (int r = 0; r < 4; ++r) {
            int rl = w * 16 + l4 * 4 + r;
            if (l15 == 0) { smp[rl] = mr[r]; slp[rl] = lr[r]; }
        }
        #pragma unroll
        for (int df = 0; df < 8; ++df)
            #pragma unroll
            for (int r = 0; r < 4; ++r) {
                int rl = w * 16 + l4 * 4 + r;
                sop[(size_t)rl * 128 + df * 16 + l15] = (__bf16)o[df][r];
            }
    }
}

// ---------------------------------------------------------------------------
// Kernel 3: combine partials for qt >= CHUNK. Grid ((64-CHUNK)*4, B); each
// block does a 16-row quarter of one qt (R15-proven parallel form).
// ---------------------------------------------------------------------------
template <int CHUNK>
__global__ __launch_bounds__(256) void combine(
    const char* __restrict__ part, float* __restrict__ out)
{
    constexpr int TASKS = tasks_per_b(CHUNK);

    const int qt  = (blockIdx.x >> 2) + CHUNK;
    const int qr  = blockIdx.x & 3;          // row quarter
    const int b   = blockIdx.y;
    const int g   = qt / CHUNK;
    const int nch = g + 1;
    const int slot0 = b * TASKS + CHUNK * g * (g + 1) / 2 + (qt % CHUNK) * nch;

    const int t   = threadIdx.x;
    const int row = qr * 16 + (t >> 4);      // 0..63
    const int c0  = (t & 15) * 8;            // 8-col strip

    float M = -INFINITY;
    for (int c = 0; c < nch; ++c) {
        const char* sp = part + (size_t)(slot0 + c) * SLOT_BYTES;
        M = fmaxf(M, ((const float*)sp)[row]);
    }
    float L = 0.f;
    for (int c = 0; c < nch; ++c) {
        const char* sp = part + (size_t)(slot0 + c) * SLOT_BYTES;
        L += ((const float*)(sp + 256))[row] * __expf(((const float*)sp)[row] - M);
    }

    float acc[8];
    #pragma unroll
    for (int i = 0; i < 8; ++i) acc[i] = 0.f;
    for (int c = 0; c < nch; ++c) {
        const char* sp = part + (size_t)(slot0 + c) * SLOT_BYTES;
        float wgt = __expf(((const float*)sp)[row] - M);
        const __bf16* op = (const __bf16*)(sp + 512) + (size_t)row * 128 + c0;
        bf16x8 vv = *(const bf16x8*)op;
        #pragma unroll
        for (int j = 0; j < 8; ++j)
            acc[j] += wgt * (float)vv[j];
    }
    float invL = 1.0f / L;
    float* o = out + ((size_t)b * SEQ + (size_t)qt * 64 + row) * DIM + c0;
    float4 f0, f1;
    f0.x = acc[0] * invL; f0.y = acc[1] * invL;
    f0.z = acc[2] * invL; f0.w = acc[3] * invL;
    f1.x = acc[4] * invL; f1.y = acc[5] * invL;
    f1.z = acc[6] * invL; f1.w = acc[7] * invL;
    *(float4*)o = f0;
    *(float4*)(o + 4) = f1;
}

// ---------------------------------------------------------------------------
extern "C" void kernel_launch(void* const* d_in, const int* in_sizes, int n_in,
                              void* d_out, int out_size, void* d_ws, size_t ws_size,
                              hipStream_t stream) {
    const float* x  = (const float*)d_in[0];
    const float* Wq = (const float*)d_in[1];
    const float* Wk = (const float*)d_in[2];
    const float* Wv = (const float*)d_in[3];
    float* out = (float*)d_out;

    __bf16* qw = (__bf16*)d_ws;
    __bf16* kw = qw + (size_t)BATCH * SEQ * DIM;
    __bf16* vw = kw + (size_t)BATCH * SEQ * DIM;
    char*   part = (char*)d_ws + QKV_BYTES;

    qkv_proj<<<dim3(BATCH * SEQ / 64, 3), 256, 0, stream>>>(x, Wq, Wk, Wv, qw, kw, vw);

    if (ws_size >= QKV_BYTES + part_bytes(4)) {
        attn<true, 4><<<dim3(tasks_per_b(4), BATCH), 256, 0, stream>>>(qw, kw, vw, out, part);
        combine<4><<<dim3(60 * 4, BATCH), 256, 0, stream>>>(part, out);
    } else if (ws_size >= QKV_BYTES + part_bytes(8)) {
        attn<true, 8><<<dim3(tasks_per_b(8), BATCH), 256, 0, stream>>>(qw, kw, vw, out, part);
        combine<8><<<dim3(56 * 4, BATCH), 256, 0, stream>>>(part, out);
    } else {
        attn<false, 8><<<dim3(SEQ / 64, BATCH), 256, 0, stream>>>(qw, kw, vw, out, part);
    }
}